// Round 10
// baseline (137.177 us; speedup 1.0000x reference)
//
#include <hip/hip_runtime.h>
#include <hip/hip_bf16.h>

typedef unsigned short ushort_t;
typedef __attribute__((ext_vector_type(8))) short short8;
typedef __attribute__((ext_vector_type(8))) unsigned short u16x8;
typedef __attribute__((ext_vector_type(4))) float f32x4;

#define BETA 0.4f
#define EPS_C 0.05f
#define NB 8192
#define NH 1024
#define NL 2048
#define NC 5

static __device__ __forceinline__ float b2f(unsigned short u) {
    union { unsigned int i; float f; } x; x.i = ((unsigned int)u) << 16; return x.f;
}
static __device__ __forceinline__ unsigned short f2b(float f) {
    union { float f; unsigned int i; } x; x.f = f;
    unsigned int i = x.i;
    unsigned int r = (i + 0x7FFFu + ((i >> 16) & 1u)) >> 16;
    return (unsigned short)r;
}

static __device__ __forceinline__ void gload16(const ushort_t* g, ushort_t* l) {
    __builtin_amdgcn_global_load_lds((const __attribute__((address_space(1))) void*)g,
                                     (__attribute__((address_space(3))) void*)l, 16, 0, 0);
}

#define CFENCE() asm volatile("" ::: "memory")
#define MFMA16(d, a, b) __builtin_amdgcn_mfma_f32_16x16x32_bf16(a, b, d, 0, 0, 0)

// ---------------- conversion kernels ----------------
__global__ __launch_bounds__(256) void cvt_kernel(const float* __restrict__ in,
                                                  ushort_t* __restrict__ out, long n) {
    long i = ((long)blockIdx.x * 256 + threadIdx.x) * 8;
    if (i >= n) return;
    const float4 a = *(const float4*)(in + i);
    const float4 b = *(const float4*)(in + i + 4);
    u16x8 o;
    o[0] = f2b(a.x); o[1] = f2b(a.y); o[2] = f2b(a.z); o[3] = f2b(a.w);
    o[4] = f2b(b.x); o[5] = f2b(b.y); o[6] = f2b(b.z); o[7] = f2b(b.w);
    *(u16x8*)(out + i) = o;
}

// W1 [2048,1024] -> W1Tb [1024,2048] AND W1b [2048,1024] (fused cast)
__global__ __launch_bounds__(256) void trans_kernel(const float* __restrict__ W1,
                                                    ushort_t* __restrict__ W1Tb,
                                                    ushort_t* __restrict__ W1b) {
    __shared__ float tile[32][33];
    const int tx = threadIdx.x & 31, ty = threadIdx.x >> 5;
    const int k0 = blockIdx.x * 32, n0 = blockIdx.y * 32;
#pragma unroll
    for (int i = 0; i < 4; ++i) {
        const float v = W1[(size_t)(k0 + ty + i * 8) * NH + n0 + tx];
        tile[ty + i * 8][tx] = v;
        W1b[(size_t)(k0 + ty + i * 8) * NH + n0 + tx] = f2b(v);
    }
    __syncthreads();
#pragma unroll
    for (int i = 0; i < 4; ++i)
        W1Tb[(size_t)(n0 + ty + i * 8) * NL + k0 + tx] = f2b(tile[tx][ty + i * 8]);
}

// ============ 128x128 GEMM, BK=32, TRIPLE-buffered distance-2 prefetch ============
// Per tile: vmcnt(4) [drains stage(t), issued 2 tiles ago; stage(t+1) stays in flight]
//           -> barrier -> stage(t+2) -> ds_read frags(t) -> 16 MFMA.  1 barrier/tile.
// LDS: pair-packed 128B lines (2 rows x 32k), slot sl=((row&1)<<2)|fg, phys=sl^(r1&7)
//      -> 2-way bank aliasing (free).  3 bufs x 16KB = 48KB -> 2-3 blocks/CU.
// EPI 0: GEMM1  A=xb[8192,2048] Bt=W1Tb[1024,2048]  grid 512, tanh -> hout
// EPI 1: GEMM2  A=vb[8192,1024] Bt=W1b [2048,1024]  grid 1024, row |.| partials
template <int EPI>
__global__ __launch_bounds__(256, 2) void g3buf(const ushort_t* __restrict__ A,
                                                const ushort_t* __restrict__ Bt,
                                                const float* __restrict__ b1,
                                                ushort_t* __restrict__ hout,
                                                float* __restrict__ partout) {
    constexpr int K  = (EPI == 0) ? 2048 : 1024;
    constexpr int NT = K / 32;                     // 64 / 32

    __shared__ ushort_t As[3][4096];   // 128 x 32 pair-packed (8KB each)
    __shared__ ushort_t Bs[3][4096];

    const int tid = threadIdx.x;
    const int wv = tid >> 6, lane = tid & 63;
    const int wm = (wv >> 1) & 1, wn = wv & 1;     // wave tile 64x64
    const int fr = lane & 15, fg = lane >> 4;

    const int xcd = blockIdx.x & 7, loc = blockIdx.x >> 3;
    const int bmLoc = (EPI == 0) ? (loc >> 3) : (loc >> 4);
    const int bnIdx = (EPI == 0) ? (loc & 7) : (loc & 15);
    const int bm0 = (xcd * 8 + bmLoc) * 128;
    const int bn0 = bnIdx * 128;

    // staging source (per lane), pair-packed: j in {0,1} covers 64 lines
    const int t8 = tid >> 3, t7 = tid & 7;

#define STA(BUF, KT) {                                                      \
    _Pragma("unroll") for (int j_ = 0; j_ < 2; ++j_) {                      \
        const int r1_ = j_ * 32 + t8;                                       \
        const int sl_ = t7 ^ (r1_ & 7);                                     \
        const int row_ = 2 * r1_ + (sl_ >> 2);                              \
        const int col_ = (KT) * 32 + (sl_ & 3) * 8;                         \
        gload16(A + (size_t)(bm0 + row_) * K + col_,                        \
                &As[BUF][j_ * 2048 + wv * 512]);                            \
    } }
#define STB(BUF, KT) {                                                      \
    _Pragma("unroll") for (int j_ = 0; j_ < 2; ++j_) {                      \
        const int r1_ = j_ * 32 + t8;                                       \
        const int sl_ = t7 ^ (r1_ & 7);                                     \
        const int row_ = 2 * r1_ + (sl_ >> 2);                              \
        const int col_ = (KT) * 32 + (sl_ & 3) * 8;                         \
        gload16(Bt + (size_t)(bn0 + row_) * K + col_,                       \
                &Bs[BUF][j_ * 2048 + wv * 512]);                            \
    } }

    auto ldA = [&](int buf, int mf) -> short8 {
        const int row = wm * 64 + mf * 16 + fr;
        const int r1 = row >> 1;
        const int phys = ((((row & 1) << 2) | fg) ^ (r1 & 7));
        return *(const short8*)&As[buf][r1 * 64 + phys * 8];
    };
    auto ldB = [&](int buf, int nf) -> short8 {
        const int row = wn * 64 + nf * 16 + fr;
        const int r1 = row >> 1;
        const int phys = ((((row & 1) << 2) | fg) ^ (r1 & 7));
        return *(const short8*)&Bs[buf][r1 * 64 + phys * 8];
    };

    f32x4 acc[4][4] = {};

    // prologue: stage groups for tiles 0 (buf0) and 1 (buf1)
    STA(0, 0) STB(0, 0)
    STA(1, 1) STB(1, 1)

#define TILE(BUF, PRE, TT) {                                                \
    const int t_ = (TT);                                                    \
    if (t_ <= NT - 2) { asm volatile("s_waitcnt vmcnt(4)" ::: "memory"); }  \
    else              { asm volatile("s_waitcnt vmcnt(0)" ::: "memory"); }  \
    CFENCE(); __builtin_amdgcn_s_barrier(); CFENCE();                       \
    if (t_ + 2 < NT) { STA(PRE, t_ + 2) STB(PRE, t_ + 2) }                  \
    short8 af[4], bf[4];                                                    \
    _Pragma("unroll") for (int m_ = 0; m_ < 4; ++m_) af[m_] = ldA(BUF, m_); \
    _Pragma("unroll") for (int n_ = 0; n_ < 4; ++n_) bf[n_] = ldB(BUF, n_); \
    __builtin_amdgcn_s_setprio(1);                                          \
    _Pragma("unroll") for (int m_ = 0; m_ < 4; ++m_)                        \
        _Pragma("unroll") for (int n_ = 0; n_ < 4; ++n_)                    \
            acc[m_][n_] = MFMA16(acc[m_][n_], af[m_], bf[n_]);              \
    __builtin_amdgcn_s_setprio(0);                                          \
    }

    int t = 0;
#pragma unroll 1
    for (; t + 3 <= NT; t += 3) {
        TILE(0, 2, t)
        TILE(1, 0, t + 1)
        TILE(2, 1, t + 2)
    }
    if (t < NT)     TILE(0, 2, t)       // NT%3==1 tail (t%3==0)
    if (t + 1 < NT) TILE(1, 0, t + 1)   // NT%3==2 tail
#undef TILE
#undef STA
#undef STB

    if constexpr (EPI == 0) {
#pragma unroll
        for (int m = 0; m < 4; ++m)
#pragma unroll
            for (int n = 0; n < 4; ++n) {
                const int col = bn0 + wn * 64 + n * 16 + fr;
                const float bb = b1[col];
                const size_t rbase = (size_t)(bm0 + wm * 64 + m * 16 + fg * 4) * NH + col;
#pragma unroll
                for (int r = 0; r < 4; ++r)
                    hout[rbase + (size_t)r * NH] = f2b(tanhf(acc[m][n][r] + bb));
            }
    } else {
        __syncthreads();
        float* rsum = (float*)&As[0][0];   // 256 floats
#pragma unroll
        for (int m = 0; m < 4; ++m)
#pragma unroll
            for (int r = 0; r < 4; ++r) {
                float s = 0.f;
#pragma unroll
                for (int n = 0; n < 4; ++n) s += fabsf(acc[m][n][r]);
                s += __shfl_xor(s, 1); s += __shfl_xor(s, 2);
                s += __shfl_xor(s, 4); s += __shfl_xor(s, 8);
                if (fr == 0) rsum[wn * 128 + wm * 64 + m * 16 + fg * 4 + r] = s;
            }
        __syncthreads();
        if (tid < 128)
            partout[(size_t)bnIdx * NB + bm0 + tid] = rsum[tid] + rsum[128 + tid];
    }
}

// ---------------- per-row kernel: logits, losses, v (transposed-W2 LDS) ----------------
__global__ __launch_bounds__(256) void rows_kernel(const ushort_t* __restrict__ hb,
                                                   const int* __restrict__ y,
                                                   const float* __restrict__ W2,
                                                   const float* __restrict__ b2,
                                                   ushort_t* __restrict__ vb,
                                                   float4* __restrict__ rowstats) {
    __shared__ float w2t[NC][NH];
    __shared__ float b2s[NC];
    const int tid = threadIdx.x;
    for (int i = tid; i < NH * NC; i += 256) w2t[i % NC][i / NC] = W2[i];
    if (tid < NC) b2s[tid] = b2[tid];
    __syncthreads();
    const int wid = tid >> 6, lane = tid & 63;
    const int row = blockIdx.x * 4 + wid;
    const ushort_t* hrow = hb + (size_t)row * NH;
    ushort_t* vrow = vb + (size_t)row * NH;
    const int yi = y[row];
    float d0 = 0, d1 = 0, d2 = 0, d3 = 0, d4 = 0;
#pragma unroll
    for (int it = 0; it < 2; ++it) {
        const int n0 = it * 512 + lane * 8;
        u16x8 hv = *(const u16x8*)(hrow + n0);
        float hh[8];
#pragma unroll
        for (int j = 0; j < 8; ++j) hh[j] = b2f(hv[j]);
#pragma unroll
        for (int c = 0; c < NC; ++c) {
            const float4 a = *(const float4*)&w2t[c][n0];
            const float4 b = *(const float4*)&w2t[c][n0 + 4];
            float d = hh[0] * a.x; d += hh[1] * a.y; d += hh[2] * a.z; d += hh[3] * a.w;
            d += hh[4] * b.x; d += hh[5] * b.y; d += hh[6] * b.z; d += hh[7] * b.w;
            if (c == 0) d0 += d; else if (c == 1) d1 += d; else if (c == 2) d2 += d;
            else if (c == 3) d3 += d; else d4 += d;
        }
        const float4 ya = *(const float4*)&w2t[yi][n0];
        const float4 yb = *(const float4*)&w2t[yi][n0 + 4];
        const float yw[8] = { ya.x, ya.y, ya.z, ya.w, yb.x, yb.y, yb.z, yb.w };
        u16x8 ov;
#pragma unroll
        for (int j = 0; j < 8; ++j)
            ov[j] = f2b((1.f - hh[j] * hh[j]) * yw[j]);
        *(u16x8*)(vrow + n0) = ov;
    }
#pragma unroll
    for (int off = 32; off; off >>= 1) {
        d0 += __shfl_xor(d0, off); d1 += __shfl_xor(d1, off); d2 += __shfl_xor(d2, off);
        d3 += __shfl_xor(d3, off); d4 += __shfl_xor(d4, off);
    }
    if (lane == 0) {
        float lg[NC] = { d0 + b2s[0], d1 + b2s[1], d2 + b2s[2], d3 + b2s[3], d4 + b2s[4] };
        float zy = lg[yi];
        float mse = 0.f, marg = 0.f;
        int amax = 0; float best = lg[0];
#pragma unroll
        for (int c = 0; c < NC; ++c) {
            float t = lg[c] - (c == yi ? 1.f : 0.f);
            mse += t * t;
            if (c != yi) marg += fmaxf(1.f - zy + lg[c], 0.f);
            if (lg[c] > best) { best = lg[c]; amax = c; }
        }
        rowstats[row] = make_float4(zy, mse, marg, (amax == yi) ? 1.f : 0.f);
    }
}

// ---------------- reductions ----------------
__global__ __launch_bounds__(256) void reduce_rows(const float4* __restrict__ rs,
                                                   const float* __restrict__ part,
                                                   int NT, float4* __restrict__ bsums) {
    const int tid = threadIdx.x;
    const int r = blockIdx.x * 256 + tid;
    float4 v = rs[r];
    float wl1 = 0.f;
    for (int t = 0; t < NT; ++t) wl1 += part[(size_t)t * NB + r];
    float R = wl1 * EPS_C / (fabsf(v.x) + 1e-8f);
    float4 s = make_float4(v.y, v.z, v.w, log1pf(R));
#pragma unroll
    for (int off = 32; off; off >>= 1) {
        s.x += __shfl_down(s.x, off); s.y += __shfl_down(s.y, off);
        s.z += __shfl_down(s.z, off); s.w += __shfl_down(s.w, off);
    }
    __shared__ float4 red[4];
    if ((tid & 63) == 0) red[tid >> 6] = s;
    __syncthreads();
    if (tid == 0) {
        float4 t = red[0];
        for (int i = 1; i < 4; ++i) { t.x += red[i].x; t.y += red[i].y; t.z += red[i].z; t.w += red[i].w; }
        bsums[blockIdx.x] = t;
    }
}

__global__ void final_combine(const float4* __restrict__ bsums, int nb, float* __restrict__ out) {
    const int l = threadIdx.x;
    float4 s = (l < nb) ? bsums[l] : make_float4(0.f, 0.f, 0.f, 0.f);
#pragma unroll
    for (int off = 32; off; off >>= 1) {
        s.x += __shfl_down(s.x, off); s.y += __shfl_down(s.y, off);
        s.z += __shfl_down(s.z, off); s.w += __shfl_down(s.w, off);
    }
    if (l == 0) {
        const float Bf = (float)NB;
        out[0] = s.x / (Bf * (float)NC) + (s.y / Bf + BETA * s.w / Bf) * (s.z / Bf);
    }
}

extern "C" void kernel_launch(void* const* d_in, const int* in_sizes, int n_in,
                              void* d_out, int out_size, void* d_ws, size_t ws_size,
                              hipStream_t stream) {
    const float* x  = (const float*)d_in[0];
    const int*   y  = (const int*)d_in[1];
    const float* W1 = (const float*)d_in[2];
    const float* b1 = (const float*)d_in[3];
    const float* W2 = (const float*)d_in[4];
    const float* b2 = (const float*)d_in[5];
    float* out = (float*)d_out;

    char* ws = (char*)d_ws;
    ushort_t* W1Tb = (ushort_t*)(ws);                           // 4MB
    ushort_t* W1b  = (ushort_t*)(ws + (4ul << 20));             // 4MB
    ushort_t* xb   = (ushort_t*)(ws + (8ul << 20));             // 32MB
    ushort_t* hb   = (ushort_t*)(ws + (40ul << 20));            // 16MB
    ushort_t* vb   = (ushort_t*)(ws + (56ul << 20));            // 16MB
    float4*   rowstats = (float4*)(ws + (72ul << 20));          // 128KB
    float*    part = (float*)(ws + (72ul << 20) + (1ul << 20)); // 512KB (16 x 8192 f32)
    float4*   bsums = (float4*)(ws + (74ul << 20));             // 512B

    // 1. conversions (W1 cast fused into transpose kernel)
    cvt_kernel<<<(NB * (long)NL) / (256 * 8), 256, 0, stream>>>(x, xb, (long)NB * NL);
    trans_kernel<<<dim3(NL / 32, NH / 32), 256, 0, stream>>>(W1, W1Tb, W1b);

    // 2. GEMM1 (3-buf distance-2): h = tanh(x @ W1 + b1)
    g3buf<0><<<512, 256, 0, stream>>>(xb, W1Tb, b1, hb, nullptr);

    // 3. per-row: logits/mse/margin/zy/correct + v
    rows_kernel<<<NB / 4, 256, 0, stream>>>(hb, y, W2, b2, vb, rowstats);

    // 4. GEMM2 (3-buf distance-2): g = v @ W1^T, row |.| partials
    g3buf<1><<<1024, 256, 0, stream>>>(vb, W1b, nullptr, nullptr, part);

    // 5. reductions
    reduce_rows<<<NB / 256, 256, 0, stream>>>(rowstats, part, NL / 128, bsums);
    final_combine<<<1, 64, 0, stream>>>(bsums, NB / 256, out);
}

// Round 11
// 113.024 us; speedup vs baseline: 1.2137x; 1.2137x over previous
//
#include <hip/hip_runtime.h>
#include <hip/hip_bf16.h>
#include <hip/hip_fp8.h>

typedef unsigned short ushort_t;
typedef unsigned char uchar_t;
typedef __attribute__((ext_vector_type(8))) short short8;
typedef __attribute__((ext_vector_type(8))) unsigned short u16x8;
typedef __attribute__((ext_vector_type(4))) float f32x4;

#define BETA 0.4f
#define EPS_C 0.05f
#define NB 8192
#define NH 1024
#define NL 2048
#define NC 5
#define VSCALE 64.0f

static __device__ __forceinline__ float b2f(unsigned short u) {
    union { unsigned int i; float f; } x; x.i = ((unsigned int)u) << 16; return x.f;
}
static __device__ __forceinline__ unsigned short f2b(float f) {
    union { float f; unsigned int i; } x; x.f = f;
    unsigned int i = x.i;
    unsigned int r = (i + 0x7FFFu + ((i >> 16) & 1u)) >> 16;
    return (unsigned short)r;
}
static __device__ __forceinline__ uchar_t f2fp8(float f) {
    __hip_fp8_e4m3 t(f);
    return (uchar_t)t.__x;
}

static __device__ __forceinline__ void gload16(const ushort_t* g, ushort_t* l) {
    __builtin_amdgcn_global_load_lds((const __attribute__((address_space(1))) void*)g,
                                     (__attribute__((address_space(3))) void*)l, 16, 0, 0);
}
static __device__ __forceinline__ void gload16b(const uchar_t* g, uchar_t* l) {
    __builtin_amdgcn_global_load_lds((const __attribute__((address_space(1))) void*)g,
                                     (__attribute__((address_space(3))) void*)l, 16, 0, 0);
}

#define CFENCE() asm volatile("" ::: "memory")
#define MFMA16(d, a, b) __builtin_amdgcn_mfma_f32_16x16x32_bf16(a, b, d, 0, 0, 0)
#define MFMA8(d, a, b)  __builtin_amdgcn_mfma_f32_16x16x32_fp8_fp8(a, b, d, 0, 0, 0)

// ---------------- conversion kernels ----------------
__global__ __launch_bounds__(256) void cvt_kernel(const float* __restrict__ in,
                                                  ushort_t* __restrict__ out, long n) {
    long i = ((long)blockIdx.x * 256 + threadIdx.x) * 8;
    if (i >= n) return;
    const float4 a = *(const float4*)(in + i);
    const float4 b = *(const float4*)(in + i + 4);
    u16x8 o;
    o[0] = f2b(a.x); o[1] = f2b(a.y); o[2] = f2b(a.z); o[3] = f2b(a.w);
    o[4] = f2b(b.x); o[5] = f2b(b.y); o[6] = f2b(b.z); o[7] = f2b(b.w);
    *(u16x8*)(out + i) = o;
}

// W1 [2048,1024] -> W1Tb bf16 [1024,2048]  AND  W1f8 = fp8(W1*64) [2048,1024]
__global__ __launch_bounds__(256) void trans_kernel(const float* __restrict__ W1,
                                                    ushort_t* __restrict__ W1Tb,
                                                    uchar_t* __restrict__ W1f8) {
    __shared__ float tile[32][33];
    const int tx = threadIdx.x & 31, ty = threadIdx.x >> 5;
    const int k0 = blockIdx.x * 32, n0 = blockIdx.y * 32;
#pragma unroll
    for (int i = 0; i < 4; ++i) {
        const float v = W1[(size_t)(k0 + ty + i * 8) * NH + n0 + tx];
        tile[ty + i * 8][tx] = v;
        W1f8[(size_t)(k0 + ty + i * 8) * NH + n0 + tx] = f2fp8(v * VSCALE);
    }
    __syncthreads();
#pragma unroll
    for (int i = 0; i < 4; ++i)
        W1Tb[(size_t)(n0 + ty + i * 8) * NL + k0 + tx] = f2b(tile[tx][ty + i * 8]);
}

// ============ GEMM1: r9-proven 128x128 dbuf bf16, 2 blocks/CU ============
__global__ __launch_bounds__(256, 2) void g128_1(const ushort_t* __restrict__ A,
                                                 const ushort_t* __restrict__ Bt,
                                                 const float* __restrict__ b1,
                                                 ushort_t* __restrict__ hout) {
    constexpr int K  = 2048;
    constexpr int NT = K / 64;

    __shared__ ushort_t As[2][8192];
    __shared__ ushort_t Bs[2][8192];

    const int tid = threadIdx.x;
    const int wv = tid >> 6, lane = tid & 63;
    const int wm = (wv >> 1) & 1, wn = wv & 1;
    const int fr = lane & 15, fg = lane >> 4;

    const int xcd = blockIdx.x & 7, loc = blockIdx.x >> 3;
    const int bm0 = (xcd * 8 + (loc >> 3)) * 128;
    const int bn0 = (loc & 7) * 128;

    const int srow = lane >> 3;
    const int scol = ((lane & 7) ^ srow) << 3;

#define STA(BUF, KT) {                                                      \
    _Pragma("unroll") for (int c_ = 0; c_ < 4; ++c_) {                      \
        const int row_ = c_ * 32 + wv * 8 + srow;                           \
        gload16(A + (size_t)(bm0 + row_) * K + (KT) * 64 + scol,            \
                &As[BUF][c_ * 2048 + wv * 512]);                            \
    } }
#define STB(BUF, KT) {                                                      \
    _Pragma("unroll") for (int c_ = 0; c_ < 4; ++c_) {                      \
        const int row_ = c_ * 32 + wv * 8 + srow;                           \
        gload16(Bt + (size_t)(bn0 + row_) * K + (KT) * 64 + scol,           \
                &Bs[BUF][c_ * 2048 + wv * 512]);                            \
    } }

    auto ldA = [&](int buf, int mf, int ks) -> short8 {
        const int row = wm * 64 + mf * 16 + fr;
        const int slot = ((ks << 2) + fg) ^ (row & 7);
        return *(const short8*)&As[buf][row * 64 + slot * 8];
    };
    auto ldB = [&](int buf, int nf, int ks) -> short8 {
        const int row = wn * 64 + nf * 16 + fr;
        const int slot = ((ks << 2) + fg) ^ (row & 7);
        return *(const short8*)&Bs[buf][row * 64 + slot * 8];
    };

    f32x4 acc[4][4] = {};

    STA(0, 0) STB(0, 0)
    asm volatile("s_waitcnt vmcnt(0)" ::: "memory");
    CFENCE(); __builtin_amdgcn_s_barrier(); CFENCE();

#define TILE(BUF, TT) {                                                     \
    const int t_ = (TT);                                                    \
    short8 af[4][2], bf[4][2];                                              \
    _Pragma("unroll") for (int n_ = 0; n_ < 4; ++n_) {                      \
        bf[n_][0] = ldB(BUF, n_, 0); bf[n_][1] = ldB(BUF, n_, 1);           \
    }                                                                       \
    _Pragma("unroll") for (int m_ = 0; m_ < 4; ++m_) {                      \
        af[m_][0] = ldA(BUF, m_, 0); af[m_][1] = ldA(BUF, m_, 1);           \
    }                                                                       \
    if (t_ + 1 < NT) { STA(BUF ^ 1, t_ + 1) STB(BUF ^ 1, t_ + 1) }          \
    CFENCE(); __builtin_amdgcn_s_barrier(); CFENCE();                       \
    __builtin_amdgcn_s_setprio(1);                                          \
    _Pragma("unroll") for (int m_ = 0; m_ < 4; ++m_)                        \
        _Pragma("unroll") for (int n_ = 0; n_ < 4; ++n_) {                  \
            acc[m_][n_] = MFMA16(acc[m_][n_], af[m_][0], bf[n_][0]);        \
            acc[m_][n_] = MFMA16(acc[m_][n_], af[m_][1], bf[n_][1]);        \
        }                                                                   \
    __builtin_amdgcn_s_setprio(0);                                          \
    asm volatile("s_waitcnt vmcnt(0)" ::: "memory");                        \
    CFENCE(); __builtin_amdgcn_s_barrier(); CFENCE();                       \
    }

#pragma unroll 1
    for (int t = 0; t < NT; t += 2) {
        TILE(0, t)
        TILE(1, t + 1)
    }
#undef TILE
#undef STA
#undef STB

#pragma unroll
    for (int m = 0; m < 4; ++m)
#pragma unroll
        for (int n = 0; n < 4; ++n) {
            const int col = bn0 + wn * 64 + n * 16 + fr;
            const float bb = b1[col];
            const size_t rbase = (size_t)(bm0 + wm * 64 + m * 16 + fg * 4) * NH + col;
#pragma unroll
            for (int r = 0; r < 4; ++r)
                hout[rbase + (size_t)r * NH] = f2b(tanhf(acc[m][n][r] + bb));
        }
}

// ============ GEMM2: fp8 e4m3, 128x128 dbuf, 32KB LDS -> up to 4 blocks/CU ============
// A = vf8 [8192,1024], Bt = W1f8 [2048,1024], both pre-scaled by 64.
// LDS: rows of 64B, pair-packed 128B lines; 8B slots, phys = sl ^ ((r1&7)<<1)
//      (same 16B-pair permutation as the proven 0-conflict bf16 layout).
__global__ __launch_bounds__(256, 4) void g2f8(const uchar_t* __restrict__ A,
                                               const uchar_t* __restrict__ Bt,
                                               float* __restrict__ partout) {
    constexpr int K  = 1024;
    constexpr int NT = K / 64;                  // 16

    __shared__ uchar_t As[2][8192];             // 128 x 64B (8KB each buf)
    __shared__ uchar_t Bs[2][8192];

    const int tid = threadIdx.x;
    const int wv = tid >> 6, lane = tid & 63;
    const int wm = (wv >> 1) & 1, wn = wv & 1;  // wave tile 64x64
    const int fr = lane & 15, fg = lane >> 4;

    const int xcd = blockIdx.x & 7, loc = blockIdx.x >> 3;
    const int bm0 = (xcd * 8 + (loc >> 4)) * 128;
    const int bnIdx = loc & 15;
    const int bn0 = bnIdx * 128;

    const int t8 = tid >> 3, t7 = tid & 7;

#define STAF(BUF, KT) {                                                     \
    _Pragma("unroll") for (int j_ = 0; j_ < 2; ++j_) {                      \
        const int r1_ = j_ * 32 + t8;                                       \
        const int sl_ = (t7 * 2) ^ ((r1_ & 7) << 1);                        \
        const int row_ = 2 * r1_ + (sl_ >> 3);                              \
        const int cb_ = (KT) * 64 + (sl_ & 7) * 8;                          \
        gload16b(A + (size_t)(bm0 + row_) * K + cb_,                        \
                 &As[BUF][j_ * 4096 + wv * 1024]);                          \
    } }
#define STBF(BUF, KT) {                                                     \
    _Pragma("unroll") for (int j_ = 0; j_ < 2; ++j_) {                      \
        const int r1_ = j_ * 32 + t8;                                       \
        const int sl_ = (t7 * 2) ^ ((r1_ & 7) << 1);                        \
        const int row_ = 2 * r1_ + (sl_ >> 3);                              \
        const int cb_ = (KT) * 64 + (sl_ & 7) * 8;                          \
        gload16b(Bt + (size_t)(bn0 + row_) * K + cb_,                       \
                 &Bs[BUF][j_ * 4096 + wv * 1024]);                          \
    } }

    auto ldA = [&](int buf, int mf, int ks) -> long {
        const int row = wm * 64 + mf * 16 + fr;
        const int r1 = row >> 1;
        const int phys = (((row & 1) << 3) | (ks << 2) | fg) ^ ((r1 & 7) << 1);
        return *(const long*)&As[buf][r1 * 128 + phys * 8];
    };
    auto ldB = [&](int buf, int nf, int ks) -> long {
        const int row = wn * 64 + nf * 16 + fr;
        const int r1 = row >> 1;
        const int phys = (((row & 1) << 3) | (ks << 2) | fg) ^ ((r1 & 7) << 1);
        return *(const long*)&Bs[buf][r1 * 128 + phys * 8];
    };

    f32x4 acc[4][4] = {};

    STAF(0, 0) STBF(0, 0)
    asm volatile("s_waitcnt vmcnt(0)" ::: "memory");
    CFENCE(); __builtin_amdgcn_s_barrier(); CFENCE();

#define TILEF(BUF, TT) {                                                    \
    const int t_ = (TT);                                                    \
    long af[4][2], bf[4][2];                                                \
    _Pragma("unroll") for (int n_ = 0; n_ < 4; ++n_) {                      \
        bf[n_][0] = ldB(BUF, n_, 0); bf[n_][1] = ldB(BUF, n_, 1);           \
    }                                                                       \
    _Pragma("unroll") for (int m_ = 0; m_ < 4; ++m_) {                      \
        af[m_][0] = ldA(BUF, m_, 0); af[m_][1] = ldA(BUF, m_, 1);           \
    }                                                                       \
    if (t_ + 1 < NT) { STAF(BUF ^ 1, t_ + 1) STBF(BUF ^ 1, t_ + 1) }        \
    CFENCE(); __builtin_amdgcn_s_barrier(); CFENCE();                       \
    __builtin_amdgcn_s_setprio(1);                                          \
    _Pragma("unroll") for (int m_ = 0; m_ < 4; ++m_)                        \
        _Pragma("unroll") for (int n_ = 0; n_ < 4; ++n_) {                  \
            acc[m_][n_] = MFMA8(acc[m_][n_], af[m_][0], bf[n_][0]);         \
            acc[m_][n_] = MFMA8(acc[m_][n_], af[m_][1], bf[n_][1]);         \
        }                                                                   \
    __builtin_amdgcn_s_setprio(0);                                          \
    asm volatile("s_waitcnt vmcnt(0)" ::: "memory");                        \
    CFENCE(); __builtin_amdgcn_s_barrier(); CFENCE();                       \
    }

#pragma unroll 1
    for (int t = 0; t < NT; t += 2) {
        TILEF(0, t)
        TILEF(1, t + 1)
    }
#undef TILEF
#undef STAF
#undef STBF

    __syncthreads();
    float* rsum = (float*)&As[0][0];
#pragma unroll
    for (int m = 0; m < 4; ++m)
#pragma unroll
        for (int r = 0; r < 4; ++r) {
            float s = 0.f;
#pragma unroll
            for (int n = 0; n < 4; ++n) s += fabsf(acc[m][n][r]);
            s += __shfl_xor(s, 1); s += __shfl_xor(s, 2);
            s += __shfl_xor(s, 4); s += __shfl_xor(s, 8);
            if (fr == 0) rsum[wn * 128 + wm * 64 + m * 16 + fg * 4 + r] = s;
        }
    __syncthreads();
    if (tid < 128)
        partout[(size_t)bnIdx * NB + bm0 + tid] = rsum[tid] + rsum[128 + tid];
}

// ---------------- per-row kernel: logits, losses, v (fp8 out, scaled x64) ----------------
__global__ __launch_bounds__(256) void rows_kernel(const ushort_t* __restrict__ hb,
                                                   const int* __restrict__ y,
                                                   const float* __restrict__ W2,
                                                   const float* __restrict__ b2,
                                                   uchar_t* __restrict__ vb,
                                                   float4* __restrict__ rowstats) {
    __shared__ float w2t[NC][NH];
    __shared__ float b2s[NC];
    const int tid = threadIdx.x;
    for (int i = tid; i < NH * NC; i += 256) w2t[i % NC][i / NC] = W2[i];
    if (tid < NC) b2s[tid] = b2[tid];
    __syncthreads();
    const int wid = tid >> 6, lane = tid & 63;
    const int row = blockIdx.x * 4 + wid;
    const ushort_t* hrow = hb + (size_t)row * NH;
    uchar_t* vrow = vb + (size_t)row * NH;
    const int yi = y[row];
    float d0 = 0, d1 = 0, d2 = 0, d3 = 0, d4 = 0;
#pragma unroll
    for (int it = 0; it < 2; ++it) {
        const int n0 = it * 512 + lane * 8;
        u16x8 hv = *(const u16x8*)(hrow + n0);
        float hh[8];
#pragma unroll
        for (int j = 0; j < 8; ++j) hh[j] = b2f(hv[j]);
#pragma unroll
        for (int c = 0; c < NC; ++c) {
            const float4 a = *(const float4*)&w2t[c][n0];
            const float4 b = *(const float4*)&w2t[c][n0 + 4];
            float d = hh[0] * a.x; d += hh[1] * a.y; d += hh[2] * a.z; d += hh[3] * a.w;
            d += hh[4] * b.x; d += hh[5] * b.y; d += hh[6] * b.z; d += hh[7] * b.w;
            if (c == 0) d0 += d; else if (c == 1) d1 += d; else if (c == 2) d2 += d;
            else if (c == 3) d3 += d; else d4 += d;
        }
        const float4 ya = *(const float4*)&w2t[yi][n0];
        const float4 yb = *(const float4*)&w2t[yi][n0 + 4];
        const float yw[8] = { ya.x, ya.y, ya.z, ya.w, yb.x, yb.y, yb.z, yb.w };
        union { uchar_t b[8]; long l; } ov;
#pragma unroll
        for (int j = 0; j < 8; ++j)
            ov.b[j] = f2fp8((1.f - hh[j] * hh[j]) * yw[j] * VSCALE);
        *(long*)(vrow + n0) = ov.l;
    }
#pragma unroll
    for (int off = 32; off; off >>= 1) {
        d0 += __shfl_xor(d0, off); d1 += __shfl_xor(d1, off); d2 += __shfl_xor(d2, off);
        d3 += __shfl_xor(d3, off); d4 += __shfl_xor(d4, off);
    }
    if (lane == 0) {
        float lg[NC] = { d0 + b2s[0], d1 + b2s[1], d2 + b2s[2], d3 + b2s[3], d4 + b2s[4] };
        float zy = lg[yi];
        float mse = 0.f, marg = 0.f;
        int amax = 0; float best = lg[0];
#pragma unroll
        for (int c = 0; c < NC; ++c) {
            float t = lg[c] - (c == yi ? 1.f : 0.f);
            mse += t * t;
            if (c != yi) marg += fmaxf(1.f - zy + lg[c], 0.f);
            if (lg[c] > best) { best = lg[c]; amax = c; }
        }
        rowstats[row] = make_float4(zy, mse, marg, (amax == yi) ? 1.f : 0.f);
    }
}

// ---------------- reductions ----------------
__global__ __launch_bounds__(256) void reduce_rows(const float4* __restrict__ rs,
                                                   const float* __restrict__ part,
                                                   int NT, float4* __restrict__ bsums) {
    const int tid = threadIdx.x;
    const int r = blockIdx.x * 256 + tid;
    float4 v = rs[r];
    float wl1 = 0.f;
    for (int t = 0; t < NT; ++t) wl1 += part[(size_t)t * NB + r];
    wl1 *= (1.0f / (VSCALE * VSCALE));   // undo fp8 pre-scaling (64*64)
    float R = wl1 * EPS_C / (fabsf(v.x) + 1e-8f);
    float4 s = make_float4(v.y, v.z, v.w, log1pf(R));
#pragma unroll
    for (int off = 32; off; off >>= 1) {
        s.x += __shfl_down(s.x, off); s.y += __shfl_down(s.y, off);
        s.z += __shfl_down(s.z, off); s.w += __shfl_down(s.w, off);
    }
    __shared__ float4 red[4];
    if ((tid & 63) == 0) red[tid >> 6] = s;
    __syncthreads();
    if (tid == 0) {
        float4 t = red[0];
        for (int i = 1; i < 4; ++i) { t.x += red[i].x; t.y += red[i].y; t.z += red[i].z; t.w += red[i].w; }
        bsums[blockIdx.x] = t;
    }
}

__global__ void final_combine(const float4* __restrict__ bsums, int nb, float* __restrict__ out) {
    const int l = threadIdx.x;
    float4 s = (l < nb) ? bsums[l] : make_float4(0.f, 0.f, 0.f, 0.f);
#pragma unroll
    for (int off = 32; off; off >>= 1) {
        s.x += __shfl_down(s.x, off); s.y += __shfl_down(s.y, off);
        s.z += __shfl_down(s.z, off); s.w += __shfl_down(s.w, off);
    }
    if (l == 0) {
        const float Bf = (float)NB;
        out[0] = s.x / (Bf * (float)NC) + (s.y / Bf + BETA * s.w / Bf) * (s.z / Bf);
    }
}

extern "C" void kernel_launch(void* const* d_in, const int* in_sizes, int n_in,
                              void* d_out, int out_size, void* d_ws, size_t ws_size,
                              hipStream_t stream) {
    const float* x  = (const float*)d_in[0];
    const int*   y  = (const int*)d_in[1];
    const float* W1 = (const float*)d_in[2];
    const float* b1 = (const float*)d_in[3];
    const float* W2 = (const float*)d_in[4];
    const float* b2 = (const float*)d_in[5];
    float* out = (float*)d_out;

    char* ws = (char*)d_ws;
    ushort_t* W1Tb = (ushort_t*)(ws);                           // 4MB
    uchar_t*  W1f8 = (uchar_t*)(ws + (4ul << 20));              // 2MB
    ushort_t* xb   = (ushort_t*)(ws + (8ul << 20));             // 32MB
    ushort_t* hb   = (ushort_t*)(ws + (40ul << 20));            // 16MB
    uchar_t*  vf8  = (uchar_t*)(ws + (56ul << 20));             // 8MB
    float4*   rowstats = (float4*)(ws + (72ul << 20));          // 128KB
    float*    part = (float*)(ws + (72ul << 20) + (1ul << 20)); // 512KB
    float4*   bsums = (float4*)(ws + (74ul << 20));             // 512B

    // 1. conversions
    cvt_kernel<<<(NB * (long)NL) / (256 * 8), 256, 0, stream>>>(x, xb, (long)NB * NL);
    trans_kernel<<<dim3(NL / 32, NH / 32), 256, 0, stream>>>(W1, W1Tb, W1f8);

    // 2. GEMM1 (bf16, r9-proven): h = tanh(x @ W1 + b1)
    g128_1<<<512, 256, 0, stream>>>(xb, W1Tb, b1, hb);

    // 3. per-row: logits/mse/margin/zy/correct + v (fp8, x64)
    rows_kernel<<<NB / 4, 256, 0, stream>>>(hb, y, W2, b2, vf8, rowstats);

    // 4. GEMM2 (fp8): g = v @ W1^T, row |.| partials
    g2f8<<<1024, 256, 0, stream>>>(vf8, W1f8, part);

    // 5. reductions
    reduce_rows<<<NB / 256, 256, 0, stream>>>(rowstats, part, NL / 128, bsums);
    final_combine<<<1, 64, 0, stream>>>(bsums, NB / 256, out);
}